// Round 2
// baseline (232.651 us; speedup 1.0000x reference)
//
#include <hip/hip_runtime.h>
#include <hip/hip_bf16.h>

#define DIM 768
#define HEADS 12
#define HD 64
#define SEQ 2048
#define BATCH 4
#define BHN 48          // BATCH*HEADS
#define TOK 8192        // BATCH*SEQ

#if __has_builtin(__builtin_amdgcn_exp2f)
#define EXP2F __builtin_amdgcn_exp2f
#else
#define EXP2F exp2f
#endif
// exp(s*0.125) = 2^(s * 0.125 * log2(e)); folded into Q at the QKV epilogue.
#define EXP_C 0.1803368801111244f

using short8  = __attribute__((ext_vector_type(8))) short;
using float4v = __attribute__((ext_vector_type(4))) float;

__device__ __forceinline__ short f2b(float f) {
    union { float f; unsigned u; } v; v.f = f;
    unsigned r = v.u + 0x7FFF + ((v.u >> 16) & 1);
    return (short)(r >> 16);
}
__device__ __forceinline__ float b2f(short s) {
    union { unsigned u; float f; } v;
    v.u = ((unsigned)(unsigned short)s) << 16;
    return v.f;
}
// pack two floats to bf16x2 (round-half-up)
__device__ __forceinline__ unsigned pk2(float a, float b) {
    union { float f; unsigned u; } x, y; x.f = a; y.f = b;
    return ((x.u + 0x8000u) >> 16) | ((y.u + 0x8000u) & 0xFFFF0000u);
}

// async global->LDS copy, 16B per lane; LDS dest = uniform base + lane*16
// NOTE: one instruction covers 64 lanes x 16 B = 1024 B = 512 shorts.
typedef const __attribute__((address_space(1))) unsigned GU;
typedef __attribute__((address_space(3))) unsigned LU;
__device__ __forceinline__ void gload_lds16(const short* g, short* l) {
    __builtin_amdgcn_global_load_lds((GU*)g, (LU*)l, 16, 0, 0);
}

// ---------------- fp32 -> bf16 cast, all three tensors in one launch ----------------
__global__ void cast_all(const float* __restrict__ x, const float* __restrict__ wq,
                         const float* __restrict__ wp,
                         short* __restrict__ xb, short* __restrict__ wqb,
                         short* __restrict__ wpb, int nx4, int nq4) {
    int i = blockIdx.x * 256 + threadIdx.x;
    const float* in; short* out; int j = i;
    if (i < nx4)            { in = x;  out = xb;  }
    else if (i < nx4 + nq4) { in = wq; out = wqb; j = i - nx4; }
    else                    { in = wp; out = wpb; j = i - nx4 - nq4; }
    float4 f = ((const float4*)in)[j];
    short4 o;
    o.x = f2b(f.x); o.y = f2b(f.y); o.z = f2b(f.z); o.w = f2b(f.w);
    ((short4*)out)[j] = o;
}

// ---------------- V column-sum: Vsum[bh*64+d] = sum_n V[bh][d][n] ----------------
__global__ void vsum_kernel(const short* __restrict__ Vw, float* __restrict__ Vsum) {
    int wid  = blockIdx.x * 4 + (threadIdx.x >> 6);   // one wave per row, 3072 rows
    int lane = threadIdx.x & 63;
    const short* row = Vw + (size_t)wid * SEQ;
    float s = 0.f;
    for (int i = lane; i < SEQ; i += 64) s += b2f(row[i]);
    #pragma unroll
    for (int m = 1; m < 64; m <<= 1) s += __shfl_xor(s, m, 64);
    if (lane == 0) Vsum[wid] = s;
}

// ---------------- QKV GEMM, 128x128 tile, BK=64 (two 32-col subtiles) ----------------
// 1D grid 1152, XCD-swizzled: ybl=(gid&7)*8+(w&7), xbl=w>>3 (w=gid>>3).
// xbl 0..11: rows=x tokens, cols=Wqk -> Q (pre-scaled EXP_C) / K.
// xbl 12..17: rows=Wv, cols=x tokens -> V^T directly (32B segments).
__global__ __launch_bounds__(256, 4)
void gemm_qkv(const short* __restrict__ A, const short* __restrict__ Bw,
              short* __restrict__ Qw, short* __restrict__ Kw, short* __restrict__ Vw)
{
    __shared__ __align__(16) short As[2][128 * 32];   // 16 KB
    __shared__ __align__(16) short Bs[2][128 * 32];   // 16 KB -> 32 KB total

    const int tid  = threadIdx.x;
    const int lane = tid & 63;
    const int wave = tid >> 6;
    const int wm = (wave >> 1) * 64, wn = (wave & 1) * 64;
    const int l15 = lane & 15, quad = lane >> 4;

    // XCD-locality swizzle: 8 consecutive-y blocks per XCD reuse tiles in L2
    const int gid = blockIdx.x;
    const int w   = gid >> 3;
    const int ybl = (gid & 7) * 8 + (w & 7);   // 0..63 token block
    const int xbl = w >> 3;                    // 0..17 col block

    const bool vpart = (xbl >= 12);
    const short* rowsP = vpart ? (Bw + 1536 * 768) : A;   // Wv rows | x tokens
    const short* colsP = vpart ? A : Bw;                  // x tokens | W rows
    const int m0 = vpart ? (xbl - 12) * 128 : ybl * 128;
    const int n0 = vpart ? ybl * 128 : xbl * 128;
    const int K = DIM;

    float4v acc[4][4];
    #pragma unroll
    for (int i = 0; i < 4; i++)
        #pragma unroll
        for (int j = 0; j < 4; j++)
            acc[i][j] = (float4v){0.f, 0.f, 0.f, 0.f};

    // staging map per 128x32 subtile: 512 granules of 16B; wave stages [wave*128, +128)
    const int G0 = wave * 128 + lane;
    const int G1 = G0 + 64;
    const int rA0 = G0 >> 2, cA0 = (G0 & 3) * 8;
    const int rA1 = G1 >> 2, cA1 = (G1 & 3) * 8;
    const int ldsoff = wave * 1024;   // shorts; each instr covers 512 shorts

    for (int kt = 0; kt < K; kt += 64) {
        #pragma unroll
        for (int s = 0; s < 2; s++) {
            const int kc = kt + s * 32;
            gload_lds16(&rowsP[(size_t)(m0 + rA0) * K + kc + cA0], &As[s][ldsoff]);
            gload_lds16(&rowsP[(size_t)(m0 + rA1) * K + kc + cA1], &As[s][ldsoff + 512]);
            gload_lds16(&colsP[(size_t)(n0 + rA0) * K + kc + cA0], &Bs[s][ldsoff]);
            gload_lds16(&colsP[(size_t)(n0 + rA1) * K + kc + cA1], &Bs[s][ldsoff + 512]);
        }
        __syncthreads();   // single vmcnt drain per 64-K chunk
        #pragma unroll
        for (int s = 0; s < 2; s++) {
            short8 af[4], bfr[4];
            #pragma unroll
            for (int t = 0; t < 4; t++) {
                af[t]  = *(const short8*)&As[s][(wm + t * 16 + l15) * 32 + quad * 8];
                bfr[t] = *(const short8*)&Bs[s][(wn + t * 16 + l15) * 32 + quad * 8];
            }
            #pragma unroll
            for (int tm = 0; tm < 4; tm++)
                #pragma unroll
                for (int tn = 0; tn < 4; tn++)
                    acc[tm][tn] = __builtin_amdgcn_mfma_f32_16x16x32_bf16(af[tm], bfr[tn], acc[tm][tn], 0, 0, 0);
        }
        __syncthreads();
    }

    #pragma unroll
    for (int tm = 0; tm < 4; tm++)
        #pragma unroll
        for (int tn = 0; tn < 4; tn++)
            #pragma unroll
            for (int r = 0; r < 4; r++) {
                int row = m0 + wm + tm * 16 + quad * 4 + r;
                int col = n0 + wn + tn * 16 + l15;
                float v = acc[tm][tn][r];
                if (vpart) {
                    int hh = row >> 6, d = row & 63;
                    int b = col >> 11, n = col & 2047;
                    Vw[((size_t)(b * HEADS + hh) * 64 + d) * SEQ + n] = f2b(v);
                } else {
                    int hh = (col & 767) >> 6, d = col & 63;
                    int b = row >> 11, n = row & 2047;
                    int bh = b * HEADS + hh;
                    if (col < 768) Qw[((size_t)bh * SEQ + n) * 64 + d] = f2b(v * EXP_C);
                    else           Kw[((size_t)bh * SEQ + n) * 64 + d] = f2b(v);
                }
            }
}

// ---------------- proj GEMM, 128x64 tile, BK=64, grid 768 (fully resident) ----------------
__global__ __launch_bounds__(256, 4)
void gemm_proj(const short* __restrict__ A, const short* __restrict__ Bw,
               const float* __restrict__ bias, float* __restrict__ Out)
{
    __shared__ __align__(16) short As[2][128 * 32];   // 16 KB
    __shared__ __align__(16) short Bs[2][64 * 32];    //  8 KB -> 24 KB total

    const int tid  = threadIdx.x;
    const int lane = tid & 63;
    const int wave = tid >> 6;
    const int wm = (wave >> 1) * 64, wn = (wave & 1) * 32;
    const int l15 = lane & 15, quad = lane >> 4;

    const int gid = blockIdx.x;             // 0..767
    const int w   = gid >> 3;               // 0..95
    const int ybl = (gid & 7) * 8 + (w & 7);   // 0..63 token block
    const int xbl = w >> 3;                    // 0..11 col block
    const int m0 = ybl * 128, n0 = xbl * 64;
    const int K = DIM;

    float4v acc[4][2];
    #pragma unroll
    for (int i = 0; i < 4; i++)
        #pragma unroll
        for (int j = 0; j < 2; j++)
            acc[i][j] = (float4v){0.f, 0.f, 0.f, 0.f};

    // A subtile 128x32: 512 granules, wave stages 128 (2 instrs of 512 shorts);
    // B subtile 64x32: 256 granules, wave stages 64 (1 instr of 512 shorts)
    const int GA0 = wave * 128 + lane, GA1 = GA0 + 64;
    const int rA0 = GA0 >> 2, cA0 = (GA0 & 3) * 8;
    const int rA1 = GA1 >> 2, cA1 = (GA1 & 3) * 8;
    const int GB0 = wave * 64 + lane;
    const int rB0 = GB0 >> 2, cB0 = (GB0 & 3) * 8;
    const int ldsoffA = wave * 1024, ldsoffB = wave * 512;

    for (int kt = 0; kt < K; kt += 64) {
        #pragma unroll
        for (int s = 0; s < 2; s++) {
            const int kc = kt + s * 32;
            gload_lds16(&A [(size_t)(m0 + rA0) * K + kc + cA0], &As[s][ldsoffA]);
            gload_lds16(&A [(size_t)(m0 + rA1) * K + kc + cA1], &As[s][ldsoffA + 512]);
            gload_lds16(&Bw[(size_t)(n0 + rB0) * K + kc + cB0], &Bs[s][ldsoffB]);
        }
        __syncthreads();
        #pragma unroll
        for (int s = 0; s < 2; s++) {
            short8 af[4], bfr[2];
            #pragma unroll
            for (int t = 0; t < 4; t++)
                af[t] = *(const short8*)&As[s][(wm + t * 16 + l15) * 32 + quad * 8];
            #pragma unroll
            for (int t = 0; t < 2; t++)
                bfr[t] = *(const short8*)&Bs[s][(wn + t * 16 + l15) * 32 + quad * 8];
            #pragma unroll
            for (int tm = 0; tm < 4; tm++)
                #pragma unroll
                for (int tn = 0; tn < 2; tn++)
                    acc[tm][tn] = __builtin_amdgcn_mfma_f32_16x16x32_bf16(af[tm], bfr[tn], acc[tm][tn], 0, 0, 0);
        }
        __syncthreads();
    }

    #pragma unroll
    for (int tm = 0; tm < 4; tm++)
        #pragma unroll
        for (int tn = 0; tn < 2; tn++)
            #pragma unroll
            for (int r = 0; r < 4; r++) {
                int row = m0 + wm + tm * 16 + quad * 4 + r;
                int col = n0 + wn + tn * 16 + l15;
                Out[(size_t)row * 768 + col] = acc[tm][tn][r] + bias[col];
            }
}

// ---------------- fused double-softmax attention ----------------
// Round-11: E stays in registers (no Eb LDS), and PV runs on full-rate x32
// MFMA. The QK output fragment (keys quad*4+r per 16-chunk) is converted to
// the x32 A-fragment (keys quad*8..+7 per 32-chunk) with a pure cross-lane
// permutation: permlane32_swap (A.hi<->B.lo) + shfl_xor(16) + cndmask.
//   C=[A.lo|B.lo], D=[A.hi|B.hi]; even quads take [C.x,C.y,Cx.x,Cx.y],
//   odd quads take [Dx.x,Dx.y,D.x,D.y]  (Cx/Dx = shfl_xor(.,16)).
__global__ __launch_bounds__(256, 4)
void attn_kernel(const short* __restrict__ Qw, const short* __restrict__ Kw,
                 const short* __restrict__ Vw, const float* __restrict__ Vsum,
                 short* __restrict__ Ow)
{
    __shared__ __align__(16) short KE[128 * 72];   // K tile (stride 72); init: Q stage; epi: float scratch
    __shared__ __align__(16) short Vt[64 * 136];   // V^T tile (stride 136); epi: L scratch

    const int tid  = threadIdx.x;
    const int lane = tid & 63, wave = tid >> 6;
    const int l15 = lane & 15, quad = lane >> 4;
    const int bh = blockIdx.x >> 5;
    const int n0 = (blockIdx.x & 31) * 64;
    const int wq = (wave & 2) * 16;    // wave's q-row base (0 or 32)
    const int wk = (wave & 1) * 64;    // wave's k-col half (0 or 64)

    const short* Qp = Qw + (size_t)bh * SEQ * 64;
    const short* Kp = Kw + (size_t)bh * SEQ * 64;
    const short* Vp = Vw + (size_t)bh * 64 * SEQ;

    // ones B-fragment for 16x16x32: col 0 only (l15==0), all 8 k-slots = 1.0
    short8 onesf;
    #pragma unroll
    for (int j = 0; j < 8; j++) onesf[j] = (l15 == 0) ? (short)0x3F80 : (short)0;

    // stage Q (64 rows x 64 cols) into KE (stride 72), read fragments, then free
    #pragma unroll
    for (int h = 0; h < 2; h++) {
        int c = tid + h * 256;
        int row = c >> 3, cc = (c & 7) * 8;
        *(short8*)&KE[row * 72 + cc] = *(const short8*)&Qp[(size_t)(n0 + row) * 64 + cc];
    }
    __syncthreads();
    short8 aq[2][2];
    #pragma unroll
    for (int nb = 0; nb < 2; nb++)
        #pragma unroll
        for (int kk = 0; kk < 2; kk++)
            aq[nb][kk] = *(const short8*)&KE[(wq + nb * 16 + l15) * 72 + kk * 32 + quad * 8];

    float4v Aacc[2][4], Lacc[2];
    #pragma unroll
    for (int mb = 0; mb < 2; mb++) {
        Lacc[mb] = (float4v){0.f, 0.f, 0.f, 0.f};
        #pragma unroll
        for (int t = 0; t < 4; t++) Aacc[mb][t] = (float4v){0.f, 0.f, 0.f, 0.f};
    }

    short8 kr[4], vr[4];
    #pragma unroll
    for (int h = 0; h < 4; h++) {
        int c = tid + h * 256;
        int row = c >> 3, cc = (c & 7) * 8;
        kr[h] = *(const short8*)&Kp[(size_t)row * 64 + cc];
        int vrow = c >> 4, vc = (c & 15) * 8;
        vr[h] = *(const short8*)&Vp[(size_t)vrow * SEQ + vc];
    }

    for (int kt = 0; kt < 16; kt++) {
        __syncthreads();   // (A) all waves done reading previous tile
        #pragma unroll
        for (int h = 0; h < 4; h++) {
            int c = tid + h * 256;
            int row = c >> 3, cc = (c & 7) * 8;
            *(short8*)&KE[row * 72 + cc] = kr[h];
            int vrow = c >> 4, vc = (c & 15) * 8;
            *(short8*)&Vt[vrow * 136 + vc] = vr[h];
        }
        __syncthreads();   // (B)

        if (kt < 15) {     // issue next-tile prefetch early; lands in regs (T14)
            #pragma unroll
            for (int h = 0; h < 4; h++) {
                int c = tid + h * 256;
                int row = c >> 3, cc = (c & 7) * 8;
                kr[h] = *(const short8*)&Kp[(size_t)((kt + 1) * 128 + row) * 64 + cc];
                int vrow = c >> 4, vc = (c & 15) * 8;
                vr[h] = *(const short8*)&Vp[(size_t)vrow * SEQ + (kt + 1) * 128 + vc];
            }
        }

        // QK^T (x32) + exp + pack; pe[nb][tn]: lane(l15=q,quad) holds
        // bf16 E for keys quad*4..+3 of 16-chunk tn (x=k0k1, y=k2k3)
        uint2 pe[2][4];
        #pragma unroll
        for (int tn = 0; tn < 4; tn++) {
            const int rowK = (wk + tn * 16 + l15) * 72;
            short8 b0 = *(const short8*)&KE[rowK + quad * 8];
            short8 b1 = *(const short8*)&KE[rowK + 32 + quad * 8];
            #pragma unroll
            for (int nb = 0; nb < 2; nb++) {
                float4v s = (float4v){0.f, 0.f, 0.f, 0.f};
                s = __builtin_amdgcn_mfma_f32_16x16x32_bf16(b0, aq[nb][0], s, 0, 0, 0);
                s = __builtin_amdgcn_mfma_f32_16x16x32_bf16(b1, aq[nb][1], s, 0, 0, 0);
                pe[nb][tn].x = pk2(EXP2F(s[0]), EXP2F(s[1]));
                pe[nb][tn].y = pk2(EXP2F(s[2]), EXP2F(s[3]));
            }
        }

        // cross-lane exchange -> x32 A-fragments ae32[nb][c] (keys quad*8..+7
        // within 32-chunk c); see header comment for the mapping proof
        const bool qodd = (quad & 1);
        short8 ae32[2][2];
        #pragma unroll
        for (int nb = 0; nb < 2; nb++)
            #pragma unroll
            for (int c = 0; c < 2; c++) {
                uint2 A = pe[nb][c * 2], B = pe[nb][c * 2 + 1];
                auto rx = __builtin_amdgcn_permlane32_swap(A.x, B.x, false, false);
                auto ry = __builtin_amdgcn_permlane32_swap(A.y, B.y, false, false);
                unsigned Cx_ = rx[0], Dx_ = rx[1];
                unsigned Cy_ = ry[0], Dy_ = ry[1];
                unsigned Cxs = (unsigned)__shfl_xor((int)Cx_, 16, 64);
                unsigned Cys = (unsigned)__shfl_xor((int)Cy_, 16, 64);
                unsigned Dxs = (unsigned)__shfl_xor((int)Dx_, 16, 64);
                unsigned Dys = (unsigned)__shfl_xor((int)Dy_, 16, 64);
                union { unsigned u[4]; short8 s; } uu;
                uu.u[0] = qodd ? Dxs : Cx_;
                uu.u[1] = qodd ? Dys : Cy_;
                uu.u[2] = qodd ? Dx_ : Cxs;
                uu.u[3] = qodd ? Dy_ : Cys;
                ae32[nb][c] = uu.s;
            }

        // PV + row-sum, full-rate x32 over the two 32-key chunks
        #pragma unroll
        for (int c = 0; c < 2; c++) {
            Lacc[0] = __builtin_amdgcn_mfma_f32_16x16x32_bf16(ae32[0][c], onesf, Lacc[0], 0, 0, 0);
            Lacc[1] = __builtin_amdgcn_mfma_f32_16x16x32_bf16(ae32[1][c], onesf, Lacc[1], 0, 0, 0);
            #pragma unroll
            for (int tn = 0; tn < 4; tn++) {
                short8 bv = *(const short8*)&Vt[(tn * 16 + l15) * 136 + wk + c * 32 + quad * 8];
                Aacc[0][tn] = __builtin_amdgcn_mfma_f32_16x16x32_bf16(ae32[0][c], bv, Aacc[0][tn], 0, 0, 0);
                Aacc[1][tn] = __builtin_amdgcn_mfma_f32_16x16x32_bf16(ae32[1][c], bv, Aacc[1][tn], 0, 0, 0);
            }
        }
    }

    __syncthreads();
    float* KEf = (float*)KE;
    float* Vtf = (float*)Vt;
    const int p = wave >> 1;
    if (wave & 1) {
        #pragma unroll
        for (int mb = 0; mb < 2; mb++) {
            #pragma unroll
            for (int tn = 0; tn < 4; tn++)
                #pragma unroll
                for (int r = 0; r < 4; r++)
                    KEf[(mb * 16 + tn * 4 + r) * 128 + p * 64 + lane] = Aacc[mb][tn][r];
            #pragma unroll
            for (int r = 0; r < 4; r++)
                Vtf[(mb * 4 + r) * 128 + p * 64 + lane] = Lacc[mb][r];
        }
    }
    __syncthreads();
    if (!(wave & 1)) {
        float il[2][4];
        #pragma unroll
        for (int mb = 0; mb < 2; mb++)
            #pragma unroll
            for (int r = 0; r < 4; r++) {
                float ls = Lacc[mb][r] + Vtf[(mb * 4 + r) * 128 + p * 64 + lane];
                il[mb][r] = 1.f / __shfl(ls, lane & 48, 64);
            }
        const int b = bh / HEADS, hh = bh - (bh / HEADS) * HEADS;
        #pragma unroll
        for (int tn = 0; tn < 4; tn++) {
            int d = tn * 16 + l15;
            float vs = Vsum[bh * 64 + d];
            #pragma unroll
            for (int mb = 0; mb < 2; mb++)
                #pragma unroll
                for (int r = 0; r < 4; r++) {
                    float a = Aacc[mb][tn][r] + KEf[(mb * 16 + tn * 4 + r) * 128 + p * 64 + lane];
                    int row = n0 + wq + mb * 16 + quad * 4 + r;
                    float val = (vs + a * il[mb][r]) * (1.f / 2049.f);
                    int tok = b * SEQ + row;
                    Ow[(size_t)tok * 768 + hh * 64 + d] = f2b(val);
                }
        }
    }
}

extern "C" void kernel_launch(void* const* d_in, const int* in_sizes, int n_in,
                              void* d_out, int out_size, void* d_ws, size_t ws_size,
                              hipStream_t stream) {
    const float* x      = (const float*)d_in[0];
    const float* w_qkv  = (const float*)d_in[1];
    const float* w_proj = (const float*)d_in[2];
    const float* b_proj = (const float*)d_in[3];
    float* out = (float*)d_out;

    char* ws = (char*)d_ws;
    size_t off = 0;
    auto alloc = [&](size_t bytes) {
        void* p = ws + off;
        off += (bytes + 255) & ~(size_t)255;
        return p;
    };
    short* x_bf  = (short*)alloc((size_t)TOK * DIM * 2);
    short* wq_bf = (short*)alloc((size_t)3 * DIM * DIM * 2);
    short* wp_bf = (short*)alloc((size_t)DIM * DIM * 2);
    short* Qw    = (short*)alloc((size_t)BHN * SEQ * 64 * 2);
    short* Kw    = (short*)alloc((size_t)BHN * SEQ * 64 * 2);
    short* Vw    = (short*)alloc((size_t)BHN * SEQ * 64 * 2);
    short* Ow    = (short*)alloc((size_t)TOK * DIM * 2);
    float* Vsum  = (float*)alloc((size_t)BHN * 64 * 4);

    int nx4 = TOK * DIM / 4, nq4 = 3 * DIM * DIM / 4, np4 = DIM * DIM / 4;
    int tot4 = nx4 + nq4 + np4;
    cast_all<<<tot4 / 256, 256, 0, stream>>>(x, w_qkv, w_proj, x_bf, wq_bf, wp_bf, nx4, nq4);

    gemm_qkv<<<1152, 256, 0, stream>>>(x_bf, wq_bf, Qw, Kw, Vw);

    vsum_kernel<<<BHN * 64 / 4, 256, 0, stream>>>(Vw, Vsum);

    attn_kernel<<<BHN * 32, 256, 0, stream>>>(Qw, Kw, Vw, Vsum, Ow);

    gemm_proj<<<768, 256, 0, stream>>>(Ow, wp_bf, b_proj, out);
}

// Round 3
// 219.905 us; speedup vs baseline: 1.0580x; 1.0580x over previous
//
#include <hip/hip_runtime.h>
#include <hip/hip_bf16.h>

#define DIM 768
#define HEADS 12
#define HD 64
#define SEQ 2048
#define BATCH 4
#define BHN 48          // BATCH*HEADS
#define TOK 8192        // BATCH*SEQ

#if __has_builtin(__builtin_amdgcn_exp2f)
#define EXP2F __builtin_amdgcn_exp2f
#else
#define EXP2F exp2f
#endif
// exp(s*0.125) = 2^(s * 0.125 * log2(e)); folded into Q at the QKV epilogue.
#define EXP_C 0.1803368801111244f

using short8  = __attribute__((ext_vector_type(8))) short;
using short4v = __attribute__((ext_vector_type(4))) short;
using float4v = __attribute__((ext_vector_type(4))) float;

__device__ __forceinline__ short f2b(float f) {
    union { float f; unsigned u; } v; v.f = f;
    unsigned r = v.u + 0x7FFF + ((v.u >> 16) & 1);
    return (short)(r >> 16);
}
__device__ __forceinline__ float b2f(short s) {
    union { unsigned u; float f; } v;
    v.u = ((unsigned)(unsigned short)s) << 16;
    return v.f;
}
// pack two floats to bf16x2 (round-half-up)
__device__ __forceinline__ unsigned pk2(float a, float b) {
    union { float f; unsigned u; } x, y; x.f = a; y.f = b;
    return ((x.u + 0x8000u) >> 16) | ((y.u + 0x8000u) & 0xFFFF0000u);
}

// async global->LDS copy, 16B per lane; LDS dest = uniform base + lane*16
// NOTE: one instruction covers 64 lanes x 16 B = 1024 B = 512 shorts.
typedef const __attribute__((address_space(1))) unsigned GU;
typedef __attribute__((address_space(3))) unsigned LU;
__device__ __forceinline__ void gload_lds16(const short* g, short* l) {
    __builtin_amdgcn_global_load_lds((GU*)g, (LU*)l, 16, 0, 0);
}

// ---------------- fp32 -> bf16 cast, all three tensors in one launch ----------------
__global__ void cast_all(const float* __restrict__ x, const float* __restrict__ wq,
                         const float* __restrict__ wp,
                         short* __restrict__ xb, short* __restrict__ wqb,
                         short* __restrict__ wpb, int nx4, int nq4) {
    int i = blockIdx.x * 256 + threadIdx.x;
    const float* in; short* out; int j = i;
    if (i < nx4)            { in = x;  out = xb;  }
    else if (i < nx4 + nq4) { in = wq; out = wqb; j = i - nx4; }
    else                    { in = wp; out = wpb; j = i - nx4 - nq4; }
    float4 f = ((const float4*)in)[j];
    short4 o;
    o.x = f2b(f.x); o.y = f2b(f.y); o.z = f2b(f.z); o.w = f2b(f.w);
    ((short4*)out)[j] = o;
}

// ---------------- V column-sum: Vsum[bh*64+d] = sum_n V[bh][d][n] ----------------
__global__ void vsum_kernel(const short* __restrict__ Vw, float* __restrict__ Vsum) {
    int wid  = blockIdx.x * 4 + (threadIdx.x >> 6);   // one wave per row, 3072 rows
    int lane = threadIdx.x & 63;
    const short* row = Vw + (size_t)wid * SEQ;
    float s = 0.f;
    for (int i = lane; i < SEQ; i += 64) s += b2f(row[i]);
    #pragma unroll
    for (int m = 1; m < 64; m <<= 1) s += __shfl_xor(s, m, 64);
    if (lane == 0) Vsum[wid] = s;
}

// ---------------- QKV GEMM, 128x128 tile, BK=64 (two 32-col subtiles) ----------------
// 1D grid 1152, XCD-swizzled: ybl=(gid&7)*8+(w&7), xbl=w>>3 (w=gid>>3).
// xbl 0..11: rows=x tokens, cols=Wqk -> Q (pre-scaled EXP_C) / K.
// xbl 12..17: rows=Wv, cols=x tokens -> V^T directly (32B segments).
__global__ __launch_bounds__(256, 4)
void gemm_qkv(const short* __restrict__ A, const short* __restrict__ Bw,
              short* __restrict__ Qw, short* __restrict__ Kw, short* __restrict__ Vw)
{
    __shared__ __align__(16) short As[2][128 * 32];   // 16 KB
    __shared__ __align__(16) short Bs[2][128 * 32];   // 16 KB -> 32 KB total

    const int tid  = threadIdx.x;
    const int lane = tid & 63;
    const int wave = tid >> 6;
    const int wm = (wave >> 1) * 64, wn = (wave & 1) * 64;
    const int l15 = lane & 15, quad = lane >> 4;

    // XCD-locality swizzle: 8 consecutive-y blocks per XCD reuse tiles in L2
    const int gid = blockIdx.x;
    const int w   = gid >> 3;
    const int ybl = (gid & 7) * 8 + (w & 7);   // 0..63 token block
    const int xbl = w >> 3;                    // 0..17 col block

    const bool vpart = (xbl >= 12);
    const short* rowsP = vpart ? (Bw + 1536 * 768) : A;   // Wv rows | x tokens
    const short* colsP = vpart ? A : Bw;                  // x tokens | W rows
    const int m0 = vpart ? (xbl - 12) * 128 : ybl * 128;
    const int n0 = vpart ? ybl * 128 : xbl * 128;
    const int K = DIM;

    float4v acc[4][4];
    #pragma unroll
    for (int i = 0; i < 4; i++)
        #pragma unroll
        for (int j = 0; j < 4; j++)
            acc[i][j] = (float4v){0.f, 0.f, 0.f, 0.f};

    // staging map per 128x32 subtile: 512 granules of 16B; wave stages [wave*128, +128)
    const int G0 = wave * 128 + lane;
    const int G1 = G0 + 64;
    const int rA0 = G0 >> 2, cA0 = (G0 & 3) * 8;
    const int rA1 = G1 >> 2, cA1 = (G1 & 3) * 8;
    const int ldsoff = wave * 1024;   // shorts; each instr covers 512 shorts

    for (int kt = 0; kt < K; kt += 64) {
        #pragma unroll
        for (int s = 0; s < 2; s++) {
            const int kc = kt + s * 32;
            gload_lds16(&rowsP[(size_t)(m0 + rA0) * K + kc + cA0], &As[s][ldsoff]);
            gload_lds16(&rowsP[(size_t)(m0 + rA1) * K + kc + cA1], &As[s][ldsoff + 512]);
            gload_lds16(&colsP[(size_t)(n0 + rA0) * K + kc + cA0], &Bs[s][ldsoff]);
            gload_lds16(&colsP[(size_t)(n0 + rA1) * K + kc + cA1], &Bs[s][ldsoff + 512]);
        }
        __syncthreads();   // single vmcnt drain per 64-K chunk
        #pragma unroll
        for (int s = 0; s < 2; s++) {
            short8 af[4], bfr[4];
            #pragma unroll
            for (int t = 0; t < 4; t++) {
                af[t]  = *(const short8*)&As[s][(wm + t * 16 + l15) * 32 + quad * 8];
                bfr[t] = *(const short8*)&Bs[s][(wn + t * 16 + l15) * 32 + quad * 8];
            }
            #pragma unroll
            for (int tm = 0; tm < 4; tm++)
                #pragma unroll
                for (int tn = 0; tn < 4; tn++)
                    acc[tm][tn] = __builtin_amdgcn_mfma_f32_16x16x32_bf16(af[tm], bfr[tn], acc[tm][tn], 0, 0, 0);
        }
        __syncthreads();
    }

    #pragma unroll
    for (int tm = 0; tm < 4; tm++)
        #pragma unroll
        for (int tn = 0; tn < 4; tn++)
            #pragma unroll
            for (int r = 0; r < 4; r++) {
                int row = m0 + wm + tm * 16 + quad * 4 + r;
                int col = n0 + wn + tn * 16 + l15;
                float v = acc[tm][tn][r];
                if (vpart) {
                    int hh = row >> 6, d = row & 63;
                    int b = col >> 11, n = col & 2047;
                    Vw[((size_t)(b * HEADS + hh) * 64 + d) * SEQ + n] = f2b(v);
                } else {
                    int hh = (col & 767) >> 6, d = col & 63;
                    int b = row >> 11, n = row & 2047;
                    int bh = b * HEADS + hh;
                    if (col < 768) Qw[((size_t)bh * SEQ + n) * 64 + d] = f2b(v * EXP_C);
                    else           Kw[((size_t)bh * SEQ + n) * 64 + d] = f2b(v);
                }
            }
}

// ---------------- proj GEMM, 128x64 tile, BK=64, grid 768 (fully resident) ----------------
__global__ __launch_bounds__(256, 4)
void gemm_proj(const short* __restrict__ A, const short* __restrict__ Bw,
               const float* __restrict__ bias, float* __restrict__ Out)
{
    __shared__ __align__(16) short As[2][128 * 32];   // 16 KB
    __shared__ __align__(16) short Bs[2][64 * 32];    //  8 KB -> 24 KB total

    const int tid  = threadIdx.x;
    const int lane = tid & 63;
    const int wave = tid >> 6;
    const int wm = (wave >> 1) * 64, wn = (wave & 1) * 32;
    const int l15 = lane & 15, quad = lane >> 4;

    const int gid = blockIdx.x;             // 0..767
    const int w   = gid >> 3;               // 0..95
    const int ybl = (gid & 7) * 8 + (w & 7);   // 0..63 token block
    const int xbl = w >> 3;                    // 0..11 col block
    const int m0 = ybl * 128, n0 = xbl * 64;
    const int K = DIM;

    float4v acc[4][2];
    #pragma unroll
    for (int i = 0; i < 4; i++)
        #pragma unroll
        for (int j = 0; j < 2; j++)
            acc[i][j] = (float4v){0.f, 0.f, 0.f, 0.f};

    // A subtile 128x32: 512 granules, wave stages 128 (2 instrs of 512 shorts);
    // B subtile 64x32: 256 granules, wave stages 64 (1 instr of 512 shorts)
    const int GA0 = wave * 128 + lane, GA1 = GA0 + 64;
    const int rA0 = GA0 >> 2, cA0 = (GA0 & 3) * 8;
    const int rA1 = GA1 >> 2, cA1 = (GA1 & 3) * 8;
    const int GB0 = wave * 64 + lane;
    const int rB0 = GB0 >> 2, cB0 = (GB0 & 3) * 8;
    const int ldsoffA = wave * 1024, ldsoffB = wave * 512;

    for (int kt = 0; kt < K; kt += 64) {
        #pragma unroll
        for (int s = 0; s < 2; s++) {
            const int kc = kt + s * 32;
            gload_lds16(&A [(size_t)(m0 + rA0) * K + kc + cA0], &As[s][ldsoffA]);
            gload_lds16(&A [(size_t)(m0 + rA1) * K + kc + cA1], &As[s][ldsoffA + 512]);
            gload_lds16(&Bw[(size_t)(n0 + rB0) * K + kc + cB0], &Bs[s][ldsoffB]);
        }
        __syncthreads();
        #pragma unroll
        for (int s = 0; s < 2; s++) {
            short8 af[4], bfr[2];
            #pragma unroll
            for (int t = 0; t < 4; t++)
                af[t] = *(const short8*)&As[s][(wm + t * 16 + l15) * 32 + quad * 8];
            #pragma unroll
            for (int t = 0; t < 2; t++)
                bfr[t] = *(const short8*)&Bs[s][(wn + t * 16 + l15) * 32 + quad * 8];
            #pragma unroll
            for (int tm = 0; tm < 4; tm++)
                #pragma unroll
                for (int tn = 0; tn < 2; tn++)
                    acc[tm][tn] = __builtin_amdgcn_mfma_f32_16x16x32_bf16(af[tm], bfr[tn], acc[tm][tn], 0, 0, 0);
        }
        __syncthreads();
    }

    #pragma unroll
    for (int tm = 0; tm < 4; tm++)
        #pragma unroll
        for (int tn = 0; tn < 2; tn++)
            #pragma unroll
            for (int r = 0; r < 4; r++) {
                int row = m0 + wm + tm * 16 + quad * 4 + r;
                int col = n0 + wn + tn * 16 + l15;
                Out[(size_t)row * 768 + col] = acc[tm][tn][r] + bias[col];
            }
}

// ---------------- fused double-softmax attention ----------------
// Round-12: permuted-k PV. MFMA sums over k-slots, so any key permutation
// shared by the A and B fragments is exact. We keep E in registers in its
// NATURAL post-QK ownership: lane (l15=q, quad) holds keys
//   {c*32 + quad*4 + 0..3}  (from x16-chunk tn=2c)
//   {c*32 + 16 + quad*4 + 0..3}  (from tn=2c+1)
// and declare those the 8 k-slots of the x32 A-fragment (zero cross-lane ops).
// V is staged into LDS with the SAME permuted key order (write-side split:
// each 8-key group lands as two 4-key b64 writes at P1, P1+8 where
// P1 = chunkbase + ((w0&8)<<1 | (w0&16)>>2)), so PV reads one b128 at quad*8.
// The ones-vector L-sum is permutation-invariant.
__global__ __launch_bounds__(256, 4)
void attn_kernel(const short* __restrict__ Qw, const short* __restrict__ Kw,
                 const short* __restrict__ Vw, const float* __restrict__ Vsum,
                 short* __restrict__ Ow)
{
    __shared__ __align__(16) short KE[128 * 72];   // K tile (stride 72); init: Q stage; epi: float scratch
    __shared__ __align__(16) short Vt[64 * 136];   // V^T tile (stride 136, permuted keys); epi: L scratch

    const int tid  = threadIdx.x;
    const int lane = tid & 63, wave = tid >> 6;
    const int l15 = lane & 15, quad = lane >> 4;
    const int bh = blockIdx.x >> 5;
    const int n0 = (blockIdx.x & 31) * 64;
    const int wq = (wave & 2) * 16;    // wave's q-row base (0 or 32)
    const int wk = (wave & 1) * 64;    // wave's k-col half (0 or 64)

    const short* Qp = Qw + (size_t)bh * SEQ * 64;
    const short* Kp = Kw + (size_t)bh * SEQ * 64;
    const short* Vp = Vw + (size_t)bh * 64 * SEQ;

    // ones B-fragment for 16x16x32: col 0 only (l15==0), all 8 k-slots = 1.0
    short8 onesf;
    #pragma unroll
    for (int j = 0; j < 8; j++) onesf[j] = (l15 == 0) ? (short)0x3F80 : (short)0;

    // stage Q (64 rows x 64 cols) into KE (stride 72), read fragments, then free
    #pragma unroll
    for (int h = 0; h < 2; h++) {
        int c = tid + h * 256;
        int row = c >> 3, cc = (c & 7) * 8;
        *(short8*)&KE[row * 72 + cc] = *(const short8*)&Qp[(size_t)(n0 + row) * 64 + cc];
    }
    __syncthreads();
    short8 aq[2][2];
    #pragma unroll
    for (int nb = 0; nb < 2; nb++)
        #pragma unroll
        for (int kk = 0; kk < 2; kk++)
            aq[nb][kk] = *(const short8*)&KE[(wq + nb * 16 + l15) * 72 + kk * 32 + quad * 8];

    float4v Aacc[2][4], Lacc[2];
    #pragma unroll
    for (int mb = 0; mb < 2; mb++) {
        Lacc[mb] = (float4v){0.f, 0.f, 0.f, 0.f};
        #pragma unroll
        for (int t = 0; t < 4; t++) Aacc[mb][t] = (float4v){0.f, 0.f, 0.f, 0.f};
    }

    // V staging geometry (permuted key positions), constant across kt
    const int svc   = ((tid & 15) * 8);          // key base 0..120
    const int svrow = tid >> 4;                  // base d-row for h-strided writes
    const int sw0   = svc & 31;
    const int svp1  = (svc & 96) + (((sw0 & 8) << 1) | ((sw0 & 16) >> 2));

    short8 kr[4], vr[4];
    #pragma unroll
    for (int h = 0; h < 4; h++) {
        int c = tid + h * 256;
        int row = c >> 3, cc = (c & 7) * 8;
        kr[h] = *(const short8*)&Kp[(size_t)row * 64 + cc];
        int vrow = c >> 4, vc = (c & 15) * 8;
        vr[h] = *(const short8*)&Vp[(size_t)vrow * SEQ + vc];
    }

    for (int kt = 0; kt < 16; kt++) {
        __syncthreads();   // (A) all waves done reading previous tile
        #pragma unroll
        for (int h = 0; h < 4; h++) {
            int c = tid + h * 256;
            int row = c >> 3, cc = (c & 7) * 8;
            *(short8*)&KE[row * 72 + cc] = kr[h];
            // permuted V store: keys svc..+3 -> svp1, keys svc+4..+7 -> svp1+8
            int vrow = svrow + h * 16;
            short4v lo = __builtin_shufflevector(vr[h], vr[h], 0, 1, 2, 3);
            short4v hi = __builtin_shufflevector(vr[h], vr[h], 4, 5, 6, 7);
            *(short4v*)&Vt[vrow * 136 + svp1]     = lo;
            *(short4v*)&Vt[vrow * 136 + svp1 + 8] = hi;
        }
        __syncthreads();   // (B)

        if (kt < 15) {     // issue next-tile prefetch early; lands in regs (T14)
            #pragma unroll
            for (int h = 0; h < 4; h++) {
                int c = tid + h * 256;
                int row = c >> 3, cc = (c & 7) * 8;
                kr[h] = *(const short8*)&Kp[(size_t)((kt + 1) * 128 + row) * 64 + cc];
                int vrow = c >> 4, vc = (c & 15) * 8;
                vr[h] = *(const short8*)&Vp[(size_t)vrow * SEQ + (kt + 1) * 128 + vc];
            }
        }

        // QK^T (x32) + exp + pack straight into permuted x32 A-fragments:
        // ae[nb][tn>>1] words (tn&1)*2, (tn&1)*2+1 <- exp of this lane's own
        // 4 scores from chunk tn (keys quad*4+r / 16+quad*4+r). No exchange.
        union AE { unsigned u[4]; short8 s; };
        AE ae[2][2];
        #pragma unroll
        for (int tn = 0; tn < 4; tn++) {
            const int rowK = (wk + tn * 16 + l15) * 72;
            short8 b0 = *(const short8*)&KE[rowK + quad * 8];
            short8 b1 = *(const short8*)&KE[rowK + 32 + quad * 8];
            #pragma unroll
            for (int nb = 0; nb < 2; nb++) {
                float4v s = (float4v){0.f, 0.f, 0.f, 0.f};
                s = __builtin_amdgcn_mfma_f32_16x16x32_bf16(b0, aq[nb][0], s, 0, 0, 0);
                s = __builtin_amdgcn_mfma_f32_16x16x32_bf16(b1, aq[nb][1], s, 0, 0, 0);
                ae[nb][tn >> 1].u[(tn & 1) * 2]     = pk2(EXP2F(s[0]), EXP2F(s[1]));
                ae[nb][tn >> 1].u[(tn & 1) * 2 + 1] = pk2(EXP2F(s[2]), EXP2F(s[3]));
            }
        }

        // PV + row-sum, full-rate x32; Vt supplies matching permuted k-order
        #pragma unroll
        for (int c2 = 0; c2 < 2; c2++) {
            Lacc[0] = __builtin_amdgcn_mfma_f32_16x16x32_bf16(ae[0][c2].s, onesf, Lacc[0], 0, 0, 0);
            Lacc[1] = __builtin_amdgcn_mfma_f32_16x16x32_bf16(ae[1][c2].s, onesf, Lacc[1], 0, 0, 0);
            #pragma unroll
            for (int tn = 0; tn < 4; tn++) {
                short8 bv = *(const short8*)&Vt[(tn * 16 + l15) * 136 + wk + c2 * 32 + quad * 8];
                Aacc[0][tn] = __builtin_amdgcn_mfma_f32_16x16x32_bf16(ae[0][c2].s, bv, Aacc[0][tn], 0, 0, 0);
                Aacc[1][tn] = __builtin_amdgcn_mfma_f32_16x16x32_bf16(ae[1][c2].s, bv, Aacc[1][tn], 0, 0, 0);
            }
        }
    }

    __syncthreads();
    float* KEf = (float*)KE;
    float* Vtf = (float*)Vt;
    const int p = wave >> 1;
    if (wave & 1) {
        #pragma unroll
        for (int mb = 0; mb < 2; mb++) {
            #pragma unroll
            for (int tn = 0; tn < 4; tn++)
                #pragma unroll
                for (int r = 0; r < 4; r++)
                    KEf[(mb * 16 + tn * 4 + r) * 128 + p * 64 + lane] = Aacc[mb][tn][r];
            #pragma unroll
            for (int r = 0; r < 4; r++)
                Vtf[(mb * 4 + r) * 128 + p * 64 + lane] = Lacc[mb][r];
        }
    }
    __syncthreads();
    if (!(wave & 1)) {
        float il[2][4];
        #pragma unroll
        for (int mb = 0; mb < 2; mb++)
            #pragma unroll
            for (int r = 0; r < 4; r++) {
                float ls = Lacc[mb][r] + Vtf[(mb * 4 + r) * 128 + p * 64 + lane];
                il[mb][r] = 1.f / __shfl(ls, lane & 48, 64);
            }
        const int b = bh / HEADS, hh = bh - (bh / HEADS) * HEADS;
        #pragma unroll
        for (int tn = 0; tn < 4; tn++) {
            int d = tn * 16 + l15;
            float vs = Vsum[bh * 64 + d];
            #pragma unroll
            for (int mb = 0; mb < 2; mb++)
                #pragma unroll
                for (int r = 0; r < 4; r++) {
                    float a = Aacc[mb][tn][r] + KEf[(mb * 16 + tn * 4 + r) * 128 + p * 64 + lane];
                    int row = n0 + wq + mb * 16 + quad * 4 + r;
                    float val = (vs + a * il[mb][r]) * (1.f / 2049.f);
                    int tok = b * SEQ + row;
                    Ow[(size_t)tok * 768 + hh * 64 + d] = f2b(val);
                }
        }
    }
}

extern "C" void kernel_launch(void* const* d_in, const int* in_sizes, int n_in,
                              void* d_out, int out_size, void* d_ws, size_t ws_size,
                              hipStream_t stream) {
    const float* x      = (const float*)d_in[0];
    const float* w_qkv  = (const float*)d_in[1];
    const float* w_proj = (const float*)d_in[2];
    const float* b_proj = (const float*)d_in[3];
    float* out = (float*)d_out;

    char* ws = (char*)d_ws;
    size_t off = 0;
    auto alloc = [&](size_t bytes) {
        void* p = ws + off;
        off += (bytes + 255) & ~(size_t)255;
        return p;
    };
    short* x_bf  = (short*)alloc((size_t)TOK * DIM * 2);
    short* wq_bf = (short*)alloc((size_t)3 * DIM * DIM * 2);
    short* wp_bf = (short*)alloc((size_t)DIM * DIM * 2);
    short* Qw    = (short*)alloc((size_t)BHN * SEQ * 64 * 2);
    short* Kw    = (short*)alloc((size_t)BHN * SEQ * 64 * 2);
    short* Vw    = (short*)alloc((size_t)BHN * SEQ * 64 * 2);
    short* Ow    = (short*)alloc((size_t)TOK * DIM * 2);
    float* Vsum  = (float*)alloc((size_t)BHN * 64 * 4);

    int nx4 = TOK * DIM / 4, nq4 = 3 * DIM * DIM / 4, np4 = DIM * DIM / 4;
    int tot4 = nx4 + nq4 + np4;
    cast_all<<<tot4 / 256, 256, 0, stream>>>(x, w_qkv, w_proj, x_bf, wq_bf, wp_bf, nx4, nq4);

    gemm_qkv<<<1152, 256, 0, stream>>>(x_bf, wq_bf, Qw, Kw, Vw);

    vsum_kernel<<<BHN * 64 / 4, 256, 0, stream>>>(Vw, Vsum);

    attn_kernel<<<BHN * 32, 256, 0, stream>>>(Qw, Kw, Vw, Vsum, Ow);

    gemm_proj<<<768, 256, 0, stream>>>(Ow, wp_bf, b_proj, out);
}

// Round 4
// 209.335 us; speedup vs baseline: 1.1114x; 1.0505x over previous
//
#include <hip/hip_runtime.h>
#include <hip/hip_bf16.h>

#define DIM 768
#define HEADS 12
#define HD 64
#define SEQ 2048
#define BATCH 4
#define BHN 48          // BATCH*HEADS
#define TOK 8192        // BATCH*SEQ

#if __has_builtin(__builtin_amdgcn_exp2f)
#define EXP2F __builtin_amdgcn_exp2f
#else
#define EXP2F exp2f
#endif
// exp(s*0.125) = 2^(s * 0.125 * log2(e)); folded into Q at the QKV epilogue.
#define EXP_C 0.1803368801111244f

using short8  = __attribute__((ext_vector_type(8))) short;
using short4v = __attribute__((ext_vector_type(4))) short;
using float4v = __attribute__((ext_vector_type(4))) float;

__device__ __forceinline__ short f2b(float f) {
    union { float f; unsigned u; } v; v.f = f;
    unsigned r = v.u + 0x7FFF + ((v.u >> 16) & 1);
    return (short)(r >> 16);
}
__device__ __forceinline__ float b2f(short s) {
    union { unsigned u; float f; } v;
    v.u = ((unsigned)(unsigned short)s) << 16;
    return v.f;
}
// pack two floats to bf16x2 (round-half-up) in ONE v_perm_b32 after the adds:
// low16 = bf16(a), high16 = bf16(b). Bit-identical to the old shift/and/or form.
__device__ __forceinline__ unsigned pk2(float a, float b) {
    union { float f; unsigned u; } x, y; x.f = a; y.f = b;
    return __builtin_amdgcn_perm(x.u + 0x8000u, y.u + 0x8000u, 0x03020706u);
}

// async global->LDS copy, 16B per lane; LDS dest = uniform base + lane*16
// NOTE: one instruction covers 64 lanes x 16 B = 1024 B = 512 shorts.
typedef const __attribute__((address_space(1))) unsigned GU;
typedef __attribute__((address_space(3))) unsigned LU;
__device__ __forceinline__ void gload_lds16(const short* g, short* l) {
    __builtin_amdgcn_global_load_lds((GU*)g, (LU*)l, 16, 0, 0);
}

// ---------------- fp32 -> bf16 cast, all three tensors in one launch ----------------
__global__ void cast_all(const float* __restrict__ x, const float* __restrict__ wq,
                         const float* __restrict__ wp,
                         short* __restrict__ xb, short* __restrict__ wqb,
                         short* __restrict__ wpb, int nx4, int nq4) {
    int i = blockIdx.x * 256 + threadIdx.x;
    const float* in; short* out; int j = i;
    if (i < nx4)            { in = x;  out = xb;  }
    else if (i < nx4 + nq4) { in = wq; out = wqb; j = i - nx4; }
    else                    { in = wp; out = wpb; j = i - nx4 - nq4; }
    float4 f = ((const float4*)in)[j];
    short4 o;
    o.x = f2b(f.x); o.y = f2b(f.y); o.z = f2b(f.z); o.w = f2b(f.w);
    ((short4*)out)[j] = o;
}

// ---------------- V column-sum: Vsum[bh*64+d] = sum_n V[bh][d][n] ----------------
__global__ void vsum_kernel(const short* __restrict__ Vw, float* __restrict__ Vsum) {
    int wid  = blockIdx.x * 4 + (threadIdx.x >> 6);   // one wave per row, 3072 rows
    int lane = threadIdx.x & 63;
    const short* row = Vw + (size_t)wid * SEQ;
    float s = 0.f;
    for (int i = lane; i < SEQ; i += 64) s += b2f(row[i]);
    #pragma unroll
    for (int m = 1; m < 64; m <<= 1) s += __shfl_xor(s, m, 64);
    if (lane == 0) Vsum[wid] = s;
}

// ---------------- QKV GEMM, 128x128 tile, BK=64 (two 32-col subtiles) ----------------
// 1D grid 1152, XCD-swizzled: ybl=(gid&7)*8+(w&7), xbl=w>>3 (w=gid>>3).
// xbl 0..11: rows=x tokens, cols=Wqk -> Q (pre-scaled EXP_C) / K.
// xbl 12..17: rows=Wv, cols=x tokens -> V^T directly (32B segments).
__global__ __launch_bounds__(256, 4)
void gemm_qkv(const short* __restrict__ A, const short* __restrict__ Bw,
              short* __restrict__ Qw, short* __restrict__ Kw, short* __restrict__ Vw)
{
    __shared__ __align__(16) short As[2][128 * 32];   // 16 KB
    __shared__ __align__(16) short Bs[2][128 * 32];   // 16 KB -> 32 KB total

    const int tid  = threadIdx.x;
    const int lane = tid & 63;
    const int wave = tid >> 6;
    const int wm = (wave >> 1) * 64, wn = (wave & 1) * 64;
    const int l15 = lane & 15, quad = lane >> 4;

    // XCD-locality swizzle: 8 consecutive-y blocks per XCD reuse tiles in L2
    const int gid = blockIdx.x;
    const int w   = gid >> 3;
    const int ybl = (gid & 7) * 8 + (w & 7);   // 0..63 token block
    const int xbl = w >> 3;                    // 0..17 col block

    const bool vpart = (xbl >= 12);
    const short* rowsP = vpart ? (Bw + 1536 * 768) : A;   // Wv rows | x tokens
    const short* colsP = vpart ? A : Bw;                  // x tokens | W rows
    const int m0 = vpart ? (xbl - 12) * 128 : ybl * 128;
    const int n0 = vpart ? ybl * 128 : xbl * 128;
    const int K = DIM;

    float4v acc[4][4];
    #pragma unroll
    for (int i = 0; i < 4; i++)
        #pragma unroll
        for (int j = 0; j < 4; j++)
            acc[i][j] = (float4v){0.f, 0.f, 0.f, 0.f};

    // staging map per 128x32 subtile: 512 granules of 16B; wave stages [wave*128, +128)
    const int G0 = wave * 128 + lane;
    const int G1 = G0 + 64;
    const int rA0 = G0 >> 2, cA0 = (G0 & 3) * 8;
    const int rA1 = G1 >> 2, cA1 = (G1 & 3) * 8;
    const int ldsoff = wave * 1024;   // shorts; each instr covers 512 shorts

    for (int kt = 0; kt < K; kt += 64) {
        #pragma unroll
        for (int s = 0; s < 2; s++) {
            const int kc = kt + s * 32;
            gload_lds16(&rowsP[(size_t)(m0 + rA0) * K + kc + cA0], &As[s][ldsoff]);
            gload_lds16(&rowsP[(size_t)(m0 + rA1) * K + kc + cA1], &As[s][ldsoff + 512]);
            gload_lds16(&colsP[(size_t)(n0 + rA0) * K + kc + cA0], &Bs[s][ldsoff]);
            gload_lds16(&colsP[(size_t)(n0 + rA1) * K + kc + cA1], &Bs[s][ldsoff + 512]);
        }
        __syncthreads();   // single vmcnt drain per 64-K chunk
        #pragma unroll
        for (int s = 0; s < 2; s++) {
            short8 af[4], bfr[4];
            #pragma unroll
            for (int t = 0; t < 4; t++) {
                af[t]  = *(const short8*)&As[s][(wm + t * 16 + l15) * 32 + quad * 8];
                bfr[t] = *(const short8*)&Bs[s][(wn + t * 16 + l15) * 32 + quad * 8];
            }
            #pragma unroll
            for (int tm = 0; tm < 4; tm++)
                #pragma unroll
                for (int tn = 0; tn < 4; tn++)
                    acc[tm][tn] = __builtin_amdgcn_mfma_f32_16x16x32_bf16(af[tm], bfr[tn], acc[tm][tn], 0, 0, 0);
        }
        __syncthreads();
    }

    #pragma unroll
    for (int tm = 0; tm < 4; tm++)
        #pragma unroll
        for (int tn = 0; tn < 4; tn++)
            #pragma unroll
            for (int r = 0; r < 4; r++) {
                int row = m0 + wm + tm * 16 + quad * 4 + r;
                int col = n0 + wn + tn * 16 + l15;
                float v = acc[tm][tn][r];
                if (vpart) {
                    int hh = row >> 6, d = row & 63;
                    int b = col >> 11, n = col & 2047;
                    Vw[((size_t)(b * HEADS + hh) * 64 + d) * SEQ + n] = f2b(v);
                } else {
                    int hh = (col & 767) >> 6, d = col & 63;
                    int b = row >> 11, n = row & 2047;
                    int bh = b * HEADS + hh;
                    if (col < 768) Qw[((size_t)bh * SEQ + n) * 64 + d] = f2b(v * EXP_C);
                    else           Kw[((size_t)bh * SEQ + n) * 64 + d] = f2b(v);
                }
            }
}

// ---------------- proj GEMM, 128x64 tile, BK=64, grid 768 (fully resident) ----------------
__global__ __launch_bounds__(256, 4)
void gemm_proj(const short* __restrict__ A, const short* __restrict__ Bw,
               const float* __restrict__ bias, float* __restrict__ Out)
{
    __shared__ __align__(16) short As[2][128 * 32];   // 16 KB
    __shared__ __align__(16) short Bs[2][64 * 32];    //  8 KB -> 24 KB total

    const int tid  = threadIdx.x;
    const int lane = tid & 63;
    const int wave = tid >> 6;
    const int wm = (wave >> 1) * 64, wn = (wave & 1) * 32;
    const int l15 = lane & 15, quad = lane >> 4;

    const int gid = blockIdx.x;             // 0..767
    const int w   = gid >> 3;               // 0..95
    const int ybl = (gid & 7) * 8 + (w & 7);   // 0..63 token block
    const int xbl = w >> 3;                    // 0..11 col block
    const int m0 = ybl * 128, n0 = xbl * 64;
    const int K = DIM;

    float4v acc[4][2];
    #pragma unroll
    for (int i = 0; i < 4; i++)
        #pragma unroll
        for (int j = 0; j < 2; j++)
            acc[i][j] = (float4v){0.f, 0.f, 0.f, 0.f};

    // A subtile 128x32: 512 granules, wave stages 128 (2 instrs of 512 shorts);
    // B subtile 64x32: 256 granules, wave stages 64 (1 instr of 512 shorts)
    const int GA0 = wave * 128 + lane, GA1 = GA0 + 64;
    const int rA0 = GA0 >> 2, cA0 = (GA0 & 3) * 8;
    const int rA1 = GA1 >> 2, cA1 = (GA1 & 3) * 8;
    const int GB0 = wave * 64 + lane;
    const int rB0 = GB0 >> 2, cB0 = (GB0 & 3) * 8;
    const int ldsoffA = wave * 1024, ldsoffB = wave * 512;

    for (int kt = 0; kt < K; kt += 64) {
        #pragma unroll
        for (int s = 0; s < 2; s++) {
            const int kc = kt + s * 32;
            gload_lds16(&A [(size_t)(m0 + rA0) * K + kc + cA0], &As[s][ldsoffA]);
            gload_lds16(&A [(size_t)(m0 + rA1) * K + kc + cA1], &As[s][ldsoffA + 512]);
            gload_lds16(&Bw[(size_t)(n0 + rB0) * K + kc + cB0], &Bs[s][ldsoffB]);
        }
        __syncthreads();
        #pragma unroll
        for (int s = 0; s < 2; s++) {
            short8 af[4], bfr[2];
            #pragma unroll
            for (int t = 0; t < 4; t++)
                af[t] = *(const short8*)&As[s][(wm + t * 16 + l15) * 32 + quad * 8];
            #pragma unroll
            for (int t = 0; t < 2; t++)
                bfr[t] = *(const short8*)&Bs[s][(wn + t * 16 + l15) * 32 + quad * 8];
            #pragma unroll
            for (int tm = 0; tm < 4; tm++)
                #pragma unroll
                for (int tn = 0; tn < 2; tn++)
                    acc[tm][tn] = __builtin_amdgcn_mfma_f32_16x16x32_bf16(af[tm], bfr[tn], acc[tm][tn], 0, 0, 0);
        }
        __syncthreads();
    }

    #pragma unroll
    for (int tm = 0; tm < 4; tm++)
        #pragma unroll
        for (int tn = 0; tn < 2; tn++)
            #pragma unroll
            for (int r = 0; r < 4; r++) {
                int row = m0 + wm + tm * 16 + quad * 4 + r;
                int col = n0 + wn + tn * 16 + l15;
                Out[(size_t)row * 768 + col] = acc[tm][tn][r] + bias[col];
            }
}

// ---------------- fused double-softmax attention ----------------
// Round-13: 128-q blocks, wave-owns-full-row.
//  - grid = 48 bh x 16 q-blocks = 768 = exactly 3 blocks/CU (no residency tail)
//  - each wave owns 32 q rows across the FULL 128-key tile (no wk split):
//    K/V staging & HBM refetch halve; epilogue needs no cross-wave reduction.
//  - permuted-k PV (round-12 scheme): lane keeps its natural post-QK keys
//    {c2*32+quad*4+0..3, c2*32+16+quad*4+0..3} as the x32 A-fragment k-slots;
//    V staged into LDS in the same permuted order (two b64 writes at svp1, +8).
//  - pk2 via v_perm_b32 (3 VALU ops), s_setprio(1) around the PV MFMA cluster.
__global__ __launch_bounds__(256, 3)
void attn_kernel(const short* __restrict__ Qw, const short* __restrict__ Kw,
                 const short* __restrict__ Vw, const float* __restrict__ Vsum,
                 short* __restrict__ Ow)
{
    __shared__ __align__(16) short KE[128 * 72];   // K tile (stride 72); init: Q stage (128x64)
    __shared__ __align__(16) short Vt[64 * 136];   // V^T tile (stride 136, permuted keys)

    const int tid  = threadIdx.x;
    const int lane = tid & 63, wave = tid >> 6;
    const int l15 = lane & 15, quad = lane >> 4;
    const int bh = blockIdx.x >> 4;            // 16 q-blocks per bh
    const int n0 = (blockIdx.x & 15) * 128;    // q-row base of this block
    const int wq = wave * 32;                  // wave's q-row base within block

    const short* Qp = Qw + (size_t)bh * SEQ * 64;
    const short* Kp = Kw + (size_t)bh * SEQ * 64;
    const short* Vp = Vw + (size_t)bh * 64 * SEQ;

    // ones B-fragment for 16x16x32: col 0 only (l15==0), all 8 k-slots = 1.0
    short8 onesf;
    #pragma unroll
    for (int j = 0; j < 8; j++) onesf[j] = (l15 == 0) ? (short)0x3F80 : (short)0;

    // stage Q (128 rows x 64 cols) into KE (stride 72), read fragments, then free
    #pragma unroll
    for (int h = 0; h < 4; h++) {
        int c = tid + h * 256;
        int row = c >> 3, cc = (c & 7) * 8;
        *(short8*)&KE[row * 72 + cc] = *(const short8*)&Qp[(size_t)(n0 + row) * 64 + cc];
    }
    __syncthreads();
    short8 aq[2][2];
    #pragma unroll
    for (int nb = 0; nb < 2; nb++)
        #pragma unroll
        for (int kk = 0; kk < 2; kk++)
            aq[nb][kk] = *(const short8*)&KE[(wq + nb * 16 + l15) * 72 + kk * 32 + quad * 8];

    float4v Aacc[2][4], Lacc[2];
    #pragma unroll
    for (int mb = 0; mb < 2; mb++) {
        Lacc[mb] = (float4v){0.f, 0.f, 0.f, 0.f};
        #pragma unroll
        for (int t = 0; t < 4; t++) Aacc[mb][t] = (float4v){0.f, 0.f, 0.f, 0.f};
    }

    // V staging geometry (permuted key positions), constant across kt
    const int svc   = ((tid & 15) * 8);          // key base 0..120
    const int svrow = tid >> 4;                  // base d-row for h-strided writes
    const int sw0   = svc & 31;
    const int svp1  = (svc & 96) + (((sw0 & 8) << 1) | ((sw0 & 16) >> 2));

    short8 kr[4], vr[4];
    #pragma unroll
    for (int h = 0; h < 4; h++) {
        int c = tid + h * 256;
        int row = c >> 3, cc = (c & 7) * 8;
        kr[h] = *(const short8*)&Kp[(size_t)row * 64 + cc];
        int vrow = c >> 4, vc = (c & 15) * 8;
        vr[h] = *(const short8*)&Vp[(size_t)vrow * SEQ + vc];
    }

    for (int kt = 0; kt < 16; kt++) {
        __syncthreads();   // (A) all waves done reading previous tile (or Q/aq)
        #pragma unroll
        for (int h = 0; h < 4; h++) {
            int c = tid + h * 256;
            int row = c >> 3, cc = (c & 7) * 8;
            *(short8*)&KE[row * 72 + cc] = kr[h];
            // permuted V store: keys svc..+3 -> svp1, keys svc+4..+7 -> svp1+8
            int vrow = svrow + h * 16;
            short4v lo = __builtin_shufflevector(vr[h], vr[h], 0, 1, 2, 3);
            short4v hi = __builtin_shufflevector(vr[h], vr[h], 4, 5, 6, 7);
            *(short4v*)&Vt[vrow * 136 + svp1]     = lo;
            *(short4v*)&Vt[vrow * 136 + svp1 + 8] = hi;
        }
        __syncthreads();   // (B)

        if (kt < 15) {     // issue next-tile prefetch early; lands in regs (T14)
            #pragma unroll
            for (int h = 0; h < 4; h++) {
                int c = tid + h * 256;
                int row = c >> 3, cc = (c & 7) * 8;
                kr[h] = *(const short8*)&Kp[(size_t)((kt + 1) * 128 + row) * 64 + cc];
                int vrow = c >> 4, vc = (c & 15) * 8;
                vr[h] = *(const short8*)&Vp[(size_t)vrow * SEQ + (kt + 1) * 128 + vc];
            }
        }

        // per 32-key chunk c2: QK^T (x32) -> exp -> perm-pack -> PV (x32).
        // c2 iterations are independent -> compiler can pipeline MFMA vs VALU.
        #pragma unroll
        for (int c2 = 0; c2 < 4; c2++) {
            union AE { unsigned u[4]; short8 s; };
            AE ae[2];
            #pragma unroll
            for (int tn2 = 0; tn2 < 2; tn2++) {
                const int tn = c2 * 2 + tn2;
                const int rowK = (tn * 16 + l15) * 72;
                short8 b0 = *(const short8*)&KE[rowK + quad * 8];
                short8 b1 = *(const short8*)&KE[rowK + 32 + quad * 8];
                #pragma unroll
                for (int nb = 0; nb < 2; nb++) {
                    float4v s = (float4v){0.f, 0.f, 0.f, 0.f};
                    s = __builtin_amdgcn_mfma_f32_16x16x32_bf16(b0, aq[nb][0], s, 0, 0, 0);
                    s = __builtin_amdgcn_mfma_f32_16x16x32_bf16(b1, aq[nb][1], s, 0, 0, 0);
                    ae[nb].u[tn2 * 2]     = pk2(EXP2F(s[0]), EXP2F(s[1]));
                    ae[nb].u[tn2 * 2 + 1] = pk2(EXP2F(s[2]), EXP2F(s[3]));
                }
            }
            __builtin_amdgcn_s_setprio(1);
            Lacc[0] = __builtin_amdgcn_mfma_f32_16x16x32_bf16(ae[0].s, onesf, Lacc[0], 0, 0, 0);
            Lacc[1] = __builtin_amdgcn_mfma_f32_16x16x32_bf16(ae[1].s, onesf, Lacc[1], 0, 0, 0);
            #pragma unroll
            for (int tn = 0; tn < 4; tn++) {
                short8 bv = *(const short8*)&Vt[(tn * 16 + l15) * 136 + c2 * 32 + quad * 8];
                Aacc[0][tn] = __builtin_amdgcn_mfma_f32_16x16x32_bf16(ae[0].s, bv, Aacc[0][tn], 0, 0, 0);
                Aacc[1][tn] = __builtin_amdgcn_mfma_f32_16x16x32_bf16(ae[1].s, bv, Aacc[1][tn], 0, 0, 0);
            }
            __builtin_amdgcn_s_setprio(0);
        }
    }

    // epilogue: wave-local. Lacc[mb][r] (at l15==0) is already the FULL row sum.
    const int b = bh / HEADS, hh = bh - (bh / HEADS) * HEADS;
    #pragma unroll
    for (int mb = 0; mb < 2; mb++)
        #pragma unroll
        for (int r = 0; r < 4; r++) {
            float il = 1.f / __shfl(Lacc[mb][r], lane & 48, 64);
            int row = n0 + wq + mb * 16 + quad * 4 + r;
            int tok = b * SEQ + row;
            #pragma unroll
            for (int tn = 0; tn < 4; tn++) {
                int d = tn * 16 + l15;
                float vs = Vsum[bh * 64 + d];
                float val = (vs + Aacc[mb][tn][r] * il) * (1.f / 2049.f);
                Ow[(size_t)tok * 768 + hh * 64 + d] = f2b(val);
            }
        }
}

extern "C" void kernel_launch(void* const* d_in, const int* in_sizes, int n_in,
                              void* d_out, int out_size, void* d_ws, size_t ws_size,
                              hipStream_t stream) {
    const float* x      = (const float*)d_in[0];
    const float* w_qkv  = (const float*)d_in[1];
    const float* w_proj = (const float*)d_in[2];
    const float* b_proj = (const float*)d_in[3];
    float* out = (float*)d_out;

    char* ws = (char*)d_ws;
    size_t off = 0;
    auto alloc = [&](size_t bytes) {
        void* p = ws + off;
        off += (bytes + 255) & ~(size_t)255;
        return p;
    };
    short* x_bf  = (short*)alloc((size_t)TOK * DIM * 2);
    short* wq_bf = (short*)alloc((size_t)3 * DIM * DIM * 2);
    short* wp_bf = (short*)alloc((size_t)DIM * DIM * 2);
    short* Qw    = (short*)alloc((size_t)BHN * SEQ * 64 * 2);
    short* Kw    = (short*)alloc((size_t)BHN * SEQ * 64 * 2);
    short* Vw    = (short*)alloc((size_t)BHN * SEQ * 64 * 2);
    short* Ow    = (short*)alloc((size_t)TOK * DIM * 2);
    float* Vsum  = (float*)alloc((size_t)BHN * 64 * 4);

    int nx4 = TOK * DIM / 4, nq4 = 3 * DIM * DIM / 4, np4 = DIM * DIM / 4;
    int tot4 = nx4 + nq4 + np4;
    cast_all<<<tot4 / 256, 256, 0, stream>>>(x, w_qkv, w_proj, x_bf, wq_bf, wp_bf, nx4, nq4);

    gemm_qkv<<<1152, 256, 0, stream>>>(x_bf, wq_bf, Qw, Kw, Vw);

    vsum_kernel<<<BHN * 64 / 4, 256, 0, stream>>>(Vw, Vsum);

    attn_kernel<<<BHN * 16, 256, 0, stream>>>(Qw, Kw, Vw, Vsum, Ow);

    gemm_proj<<<768, 256, 0, stream>>>(Ow, wp_bf, b_proj, out);
}

// Round 5
// 207.315 us; speedup vs baseline: 1.1222x; 1.0097x over previous
//
#include <hip/hip_runtime.h>
#include <hip/hip_bf16.h>

#define DIM 768
#define HEADS 12
#define HD 64
#define SEQ 2048
#define BATCH 4
#define BHN 48          // BATCH*HEADS
#define TOK 8192        // BATCH*SEQ

#if __has_builtin(__builtin_amdgcn_exp2f)
#define EXP2F __builtin_amdgcn_exp2f
#else
#define EXP2F exp2f
#endif
// exp(s*0.125) = 2^(s * 0.125 * log2(e)); folded into Q at the QKV epilogue.
#define EXP_C 0.1803368801111244f

using short8  = __attribute__((ext_vector_type(8))) short;
using short4v = __attribute__((ext_vector_type(4))) short;
using float4v = __attribute__((ext_vector_type(4))) float;

__device__ __forceinline__ short f2b(float f) {
    union { float f; unsigned u; } v; v.f = f;
    unsigned r = v.u + 0x7FFF + ((v.u >> 16) & 1);
    return (short)(r >> 16);
}
__device__ __forceinline__ float b2f(short s) {
    union { unsigned u; float f; } v;
    v.u = ((unsigned)(unsigned short)s) << 16;
    return v.f;
}
// pack two floats to bf16x2 (round-half-up) in ONE v_perm_b32 after the adds.
__device__ __forceinline__ unsigned pk2(float a, float b) {
    union { float f; unsigned u; } x, y; x.f = a; y.f = b;
    return __builtin_amdgcn_perm(x.u + 0x8000u, y.u + 0x8000u, 0x03020706u);
}

// async global->LDS copy, 16B per lane; LDS dest = uniform base + lane*16
typedef const __attribute__((address_space(1))) unsigned GU;
typedef __attribute__((address_space(3))) unsigned LU;
__device__ __forceinline__ void gload_lds16(const short* g, short* l) {
    __builtin_amdgcn_global_load_lds((GU*)g, (LU*)l, 16, 0, 0);
}

// ---------------- fp32 -> bf16 cast, all three tensors in one launch ----------------
__global__ void cast_all(const float* __restrict__ x, const float* __restrict__ wq,
                         const float* __restrict__ wp,
                         short* __restrict__ xb, short* __restrict__ wqb,
                         short* __restrict__ wpb, int nx4, int nq4) {
    int i = blockIdx.x * 256 + threadIdx.x;
    const float* in; short* out; int j = i;
    if (i < nx4)            { in = x;  out = xb;  }
    else if (i < nx4 + nq4) { in = wq; out = wqb; j = i - nx4; }
    else                    { in = wp; out = wpb; j = i - nx4 - nq4; }
    float4 f = ((const float4*)in)[j];
    short4 o;
    o.x = f2b(f.x); o.y = f2b(f.y); o.z = f2b(f.z); o.w = f2b(f.w);
    ((short4*)out)[j] = o;
}

// ---------------- V column-sum over the chunked-permuted V layout ----------------
// Vw2[(bh*64 + C)*2048 + d*32 + slot]; sum over a (bh,d) row is slot-order invariant.
__global__ void vsum_kernel(const short* __restrict__ Vw, float* __restrict__ Vsum) {
    int wid  = blockIdx.x * 4 + (threadIdx.x >> 6);   // bh*64+d, 3072 rows
    int lane = threadIdx.x & 63;
    int bh = wid >> 6, d = wid & 63;
    const short* base = Vw + (size_t)bh * (SEQ * 64) + d * 32;
    float s = 0.f;
    for (int i = lane; i < SEQ; i += 64)
        s += b2f(base[(i >> 5) * 2048 + (i & 31)]);
    #pragma unroll
    for (int m = 1; m < 64; m <<= 1) s += __shfl_xor(s, m, 64);
    if (lane == 0) Vsum[wid] = s;
}

// ---------------- QKV GEMM, 128x128 tile, BK=64 (two 32-col subtiles) ----------------
// xbl 0..11: rows=x tokens, cols=Wqk -> Q (pre-scaled EXP_C) / K.
// xbl 12..17: rows=Wv, cols=x tokens -> V in chunked-permuted layout:
//   element (d, n): C=n>>5, w=n&31, slot=((w&15)>>2)*8 + ((w&16)>>2) + (w&3)
//   Vw[(bh*64+C)*2048 + d*32 + slot]  (matches attn's permuted-k B-fragment)
__global__ __launch_bounds__(256, 4)
void gemm_qkv(const short* __restrict__ A, const short* __restrict__ Bw,
              short* __restrict__ Qw, short* __restrict__ Kw, short* __restrict__ Vw)
{
    __shared__ __align__(16) short As[2][128 * 32];   // 16 KB
    __shared__ __align__(16) short Bs[2][128 * 32];   // 16 KB -> 32 KB total

    const int tid  = threadIdx.x;
    const int lane = tid & 63;
    const int wave = tid >> 6;
    const int wm = (wave >> 1) * 64, wn = (wave & 1) * 64;
    const int l15 = lane & 15, quad = lane >> 4;

    const int gid = blockIdx.x;
    const int w   = gid >> 3;
    const int ybl = (gid & 7) * 8 + (w & 7);   // 0..63 token block
    const int xbl = w >> 3;                    // 0..17 col block

    const bool vpart = (xbl >= 12);
    const short* rowsP = vpart ? (Bw + 1536 * 768) : A;   // Wv rows | x tokens
    const short* colsP = vpart ? A : Bw;                  // x tokens | W rows
    const int m0 = vpart ? (xbl - 12) * 128 : ybl * 128;
    const int n0 = vpart ? ybl * 128 : xbl * 128;
    const int K = DIM;

    float4v acc[4][4];
    #pragma unroll
    for (int i = 0; i < 4; i++)
        #pragma unroll
        for (int j = 0; j < 4; j++)
            acc[i][j] = (float4v){0.f, 0.f, 0.f, 0.f};

    const int G0 = wave * 128 + lane;
    const int G1 = G0 + 64;
    const int rA0 = G0 >> 2, cA0 = (G0 & 3) * 8;
    const int rA1 = G1 >> 2, cA1 = (G1 & 3) * 8;
    const int ldsoff = wave * 1024;

    for (int kt = 0; kt < K; kt += 64) {
        #pragma unroll
        for (int s = 0; s < 2; s++) {
            const int kc = kt + s * 32;
            gload_lds16(&rowsP[(size_t)(m0 + rA0) * K + kc + cA0], &As[s][ldsoff]);
            gload_lds16(&rowsP[(size_t)(m0 + rA1) * K + kc + cA1], &As[s][ldsoff + 512]);
            gload_lds16(&colsP[(size_t)(n0 + rA0) * K + kc + cA0], &Bs[s][ldsoff]);
            gload_lds16(&colsP[(size_t)(n0 + rA1) * K + kc + cA1], &Bs[s][ldsoff + 512]);
        }
        __syncthreads();
        #pragma unroll
        for (int s = 0; s < 2; s++) {
            short8 af[4], bfr[4];
            #pragma unroll
            for (int t = 0; t < 4; t++) {
                af[t]  = *(const short8*)&As[s][(wm + t * 16 + l15) * 32 + quad * 8];
                bfr[t] = *(const short8*)&Bs[s][(wn + t * 16 + l15) * 32 + quad * 8];
            }
            #pragma unroll
            for (int tm = 0; tm < 4; tm++)
                #pragma unroll
                for (int tn = 0; tn < 4; tn++)
                    acc[tm][tn] = __builtin_amdgcn_mfma_f32_16x16x32_bf16(af[tm], bfr[tn], acc[tm][tn], 0, 0, 0);
        }
        __syncthreads();
    }

    #pragma unroll
    for (int tm = 0; tm < 4; tm++)
        #pragma unroll
        for (int tn = 0; tn < 4; tn++)
            #pragma unroll
            for (int r = 0; r < 4; r++) {
                int row = m0 + wm + tm * 16 + quad * 4 + r;
                int col = n0 + wn + tn * 16 + l15;
                float v = acc[tm][tn][r];
                if (vpart) {
                    int hh = row >> 6, d = row & 63;
                    int b = col >> 11, n = col & 2047;
                    int C = n >> 5, wk = n & 31;
                    int slot = ((wk & 15) >> 2) * 8 + ((wk & 16) >> 2) + (wk & 3);
                    Vw[((size_t)(b * HEADS + hh) * 64 + C) * 2048 + d * 32 + slot] = f2b(v);
                } else {
                    int hh = (col & 767) >> 6, d = col & 63;
                    int b = row >> 11, n = row & 2047;
                    int bh = b * HEADS + hh;
                    if (col < 768) Qw[((size_t)bh * SEQ + n) * 64 + d] = f2b(v * EXP_C);
                    else           Kw[((size_t)bh * SEQ + n) * 64 + d] = f2b(v);
                }
            }
}

// ---------------- proj GEMM, 128x64 tile, BK=64, grid 768 (fully resident) ----------------
__global__ __launch_bounds__(256, 4)
void gemm_proj(const short* __restrict__ A, const short* __restrict__ Bw,
               const float* __restrict__ bias, float* __restrict__ Out)
{
    __shared__ __align__(16) short As[2][128 * 32];   // 16 KB
    __shared__ __align__(16) short Bs[2][64 * 32];    //  8 KB -> 24 KB total

    const int tid  = threadIdx.x;
    const int lane = tid & 63;
    const int wave = tid >> 6;
    const int wm = (wave >> 1) * 64, wn = (wave & 1) * 32;
    const int l15 = lane & 15, quad = lane >> 4;

    const int gid = blockIdx.x;             // 0..767
    const int w   = gid >> 3;               // 0..95
    const int ybl = (gid & 7) * 8 + (w & 7);   // 0..63 token block
    const int xbl = w >> 3;                    // 0..11 col block
    const int m0 = ybl * 128, n0 = xbl * 64;
    const int K = DIM;

    float4v acc[4][2];
    #pragma unroll
    for (int i = 0; i < 4; i++)
        #pragma unroll
        for (int j = 0; j < 2; j++)
            acc[i][j] = (float4v){0.f, 0.f, 0.f, 0.f};

    const int GA0 = wave * 128 + lane, GA1 = GA0 + 64;
    const int rA0 = GA0 >> 2, cA0 = (GA0 & 3) * 8;
    const int rA1 = GA1 >> 2, cA1 = (GA1 & 3) * 8;
    const int GB0 = wave * 64 + lane;
    const int rB0 = GB0 >> 2, cB0 = (GB0 & 3) * 8;
    const int ldsoffA = wave * 1024, ldsoffB = wave * 512;

    for (int kt = 0; kt < K; kt += 64) {
        #pragma unroll
        for (int s = 0; s < 2; s++) {
            const int kc = kt + s * 32;
            gload_lds16(&A [(size_t)(m0 + rA0) * K + kc + cA0], &As[s][ldsoffA]);
            gload_lds16(&A [(size_t)(m0 + rA1) * K + kc + cA1], &As[s][ldsoffA + 512]);
            gload_lds16(&Bw[(size_t)(n0 + rB0) * K + kc + cB0], &Bs[s][ldsoffB]);
        }
        __syncthreads();
        #pragma unroll
        for (int s = 0; s < 2; s++) {
            short8 af[4], bfr[2];
            #pragma unroll
            for (int t = 0; t < 4; t++)
                af[t] = *(const short8*)&As[s][(wm + t * 16 + l15) * 32 + quad * 8];
            #pragma unroll
            for (int t = 0; t < 2; t++)
                bfr[t] = *(const short8*)&Bs[s][(wn + t * 16 + l15) * 32 + quad * 8];
            #pragma unroll
            for (int tm = 0; tm < 4; tm++)
                #pragma unroll
                for (int tn = 0; tn < 2; tn++)
                    acc[tm][tn] = __builtin_amdgcn_mfma_f32_16x16x32_bf16(af[tm], bfr[tn], acc[tm][tn], 0, 0, 0);
        }
        __syncthreads();
    }

    #pragma unroll
    for (int tm = 0; tm < 4; tm++)
        #pragma unroll
        for (int tn = 0; tn < 2; tn++)
            #pragma unroll
            for (int r = 0; r < 4; r++) {
                int row = m0 + wm + tm * 16 + quad * 4 + r;
                int col = n0 + wn + tn * 16 + l15;
                Out[(size_t)row * 768 + col] = acc[tm][tn][r] + bias[col];
            }
}

// ---------------- fused double-softmax attention ----------------
// Round-14: V bypasses LDS. The permuted-k PV B-fragment is one contiguous
// 16B global load per lane from the chunked V layout (64 lanes = 1 KB,
// perfectly coalesced, L2-resident). Only K is LDS-staged (18.4 KB total).
// bv is pipelined one 32-key chunk ahead in a 2x16-VGPR ping-pong.
// XCD head-locality swizzle: 6 heads per XCD, so the 16 q-blocks sharing a
// head's K/V hit the same L2.
__global__ __launch_bounds__(256, 3)
void attn_kernel(const short* __restrict__ Qw, const short* __restrict__ Kw,
                 const short* __restrict__ Vw, const float* __restrict__ Vsum,
                 short* __restrict__ Ow)
{
    __shared__ __align__(16) short KE[128 * 72];   // K tile (stride 72); init: Q stage (128x64)

    const int tid  = threadIdx.x;
    const int lane = tid & 63, wave = tid >> 6;
    const int l15 = lane & 15, quad = lane >> 4;
    // XCD-locality: blockIdx round-robins XCDs by (bid & 7); give each XCD 6 heads.
    const int bid = blockIdx.x;
    const int ii  = bid >> 3;                  // 0..95
    const int bh  = (bid & 7) * 6 + (ii >> 4); // head group per XCD
    const int n0  = (ii & 15) * 128;           // q-row base of this block
    const int wq  = wave * 32;                 // wave's q-row base within block

    const short* Qp = Qw + (size_t)bh * SEQ * 64;
    const short* Kp = Kw + (size_t)bh * SEQ * 64;
    const short* Vp = Vw + (size_t)bh * (SEQ * 64);

    // ones B-fragment for 16x16x32: col 0 only (l15==0), all 8 k-slots = 1.0
    short8 onesf;
    #pragma unroll
    for (int j = 0; j < 8; j++) onesf[j] = (l15 == 0) ? (short)0x3F80 : (short)0;

    // stage Q (128 rows x 64 cols) into KE (stride 72), read fragments, then free
    #pragma unroll
    for (int h = 0; h < 4; h++) {
        int c = tid + h * 256;
        int row = c >> 3, cc = (c & 7) * 8;
        *(short8*)&KE[row * 72 + cc] = *(const short8*)&Qp[(size_t)(n0 + row) * 64 + cc];
    }
    __syncthreads();
    short8 aq[2][2];
    #pragma unroll
    for (int nb = 0; nb < 2; nb++)
        #pragma unroll
        for (int kk = 0; kk < 2; kk++)
            aq[nb][kk] = *(const short8*)&KE[(wq + nb * 16 + l15) * 72 + kk * 32 + quad * 8];

    float4v Aacc[2][4], Lacc[2];
    #pragma unroll
    for (int mb = 0; mb < 2; mb++) {
        Lacc[mb] = (float4v){0.f, 0.f, 0.f, 0.f};
        #pragma unroll
        for (int t = 0; t < 4; t++) Aacc[mb][t] = (float4v){0.f, 0.f, 0.f, 0.f};
    }

    // per-lane V offset within a 32-key chunk block: d*32 + quad*8, d = tn*16+l15
    const int vlane = l15 * 32 + quad * 8;

    short8 kr[4];
    #pragma unroll
    for (int h = 0; h < 4; h++) {
        int c = tid + h * 256;
        int row = c >> 3, cc = (c & 7) * 8;
        kr[h] = *(const short8*)&Kp[(size_t)row * 64 + cc];
    }

    // V ping-pong: preload chunk 0 of kt 0
    short8 bv[2][4];
    #pragma unroll
    for (int tn = 0; tn < 4; tn++)
        bv[0][tn] = *(const short8*)&Vp[tn * 512 + vlane];

    for (int kt = 0; kt < 16; kt++) {
        __syncthreads();   // (A) all waves done reading previous K tile (or Q/aq)
        #pragma unroll
        for (int h = 0; h < 4; h++) {
            int c = tid + h * 256;
            int row = c >> 3, cc = (c & 7) * 8;
            *(short8*)&KE[row * 72 + cc] = kr[h];
        }
        __syncthreads();   // (B)

        if (kt < 15) {     // issue next K-tile prefetch early (lands in regs)
            #pragma unroll
            for (int h = 0; h < 4; h++) {
                int c = tid + h * 256;
                int row = c >> 3, cc = (c & 7) * 8;
                kr[h] = *(const short8*)&Kp[(size_t)((kt + 1) * 128 + row) * 64 + cc];
            }
        }

        // per 32-key chunk c2: QK^T (x32) -> exp -> perm-pack -> PV (x32).
        #pragma unroll
        for (int c2 = 0; c2 < 4; c2++) {
            const int cur = c2 & 1, nxt = cur ^ 1;
            // issue next chunk's V loads (global, L2) one phase ahead
            if (c2 < 3) {
                #pragma unroll
                for (int tn = 0; tn < 4; tn++)
                    bv[nxt][tn] = *(const short8*)&Vp[(kt * 4 + c2 + 1) * 2048 + tn * 512 + vlane];
            } else if (kt < 15) {
                #pragma unroll
                for (int tn = 0; tn < 4; tn++)
                    bv[nxt][tn] = *(const short8*)&Vp[(kt + 1) * 4 * 2048 + tn * 512 + vlane];
            }

            union AE { unsigned u[4]; short8 s; };
            AE ae[2];
            #pragma unroll
            for (int tn2 = 0; tn2 < 2; tn2++) {
                const int tn = c2 * 2 + tn2;
                const int rowK = (tn * 16 + l15) * 72;
                short8 b0 = *(const short8*)&KE[rowK + quad * 8];
                short8 b1 = *(const short8*)&KE[rowK + 32 + quad * 8];
                #pragma unroll
                for (int nb = 0; nb < 2; nb++) {
                    float4v s = (float4v){0.f, 0.f, 0.f, 0.f};
                    s = __builtin_amdgcn_mfma_f32_16x16x32_bf16(b0, aq[nb][0], s, 0, 0, 0);
                    s = __builtin_amdgcn_mfma_f32_16x16x32_bf16(b1, aq[nb][1], s, 0, 0, 0);
                    ae[nb].u[tn2 * 2]     = pk2(EXP2F(s[0]), EXP2F(s[1]));
                    ae[nb].u[tn2 * 2 + 1] = pk2(EXP2F(s[2]), EXP2F(s[3]));
                }
            }
            __builtin_amdgcn_s_setprio(1);
            Lacc[0] = __builtin_amdgcn_mfma_f32_16x16x32_bf16(ae[0].s, onesf, Lacc[0], 0, 0, 0);
            Lacc[1] = __builtin_amdgcn_mfma_f32_16x16x32_bf16(ae[1].s, onesf, Lacc[1], 0, 0, 0);
            #pragma unroll
            for (int tn = 0; tn < 4; tn++) {
                Aacc[0][tn] = __builtin_amdgcn_mfma_f32_16x16x32_bf16(ae[0].s, bv[cur][tn], Aacc[0][tn], 0, 0, 0);
                Aacc[1][tn] = __builtin_amdgcn_mfma_f32_16x16x32_bf16(ae[1].s, bv[cur][tn], Aacc[1][tn], 0, 0, 0);
            }
            __builtin_amdgcn_s_setprio(0);
        }
    }

    // epilogue: wave-local. Lacc[mb][r] (at l15==0) is already the FULL row sum.
    const int b = bh / HEADS, hh = bh - (bh / HEADS) * HEADS;
    #pragma unroll
    for (int mb = 0; mb < 2; mb++)
        #pragma unroll
        for (int r = 0; r < 4; r++) {
            float il = 1.f / __shfl(Lacc[mb][r], lane & 48, 64);
            int row = n0 + wq + mb * 16 + quad * 4 + r;
            int tok = b * SEQ + row;
            #pragma unroll
            for (int tn = 0; tn < 4; tn++) {
                int d = tn * 16 + l15;
                float vs = Vsum[bh * 64 + d];
                float val = (vs + Aacc[mb][tn][r] * il) * (1.f / 2049.f);
                Ow[(size_t)tok * 768 + hh * 64 + d] = f2b(val);
            }
        }
}

extern "C" void kernel_launch(void* const* d_in, const int* in_sizes, int n_in,
                              void* d_out, int out_size, void* d_ws, size_t ws_size,
                              hipStream_t stream) {
    const float* x      = (const float*)d_in[0];
    const float* w_qkv  = (const float*)d_in[1];
    const float* w_proj = (const float*)d_in[2];
    const float* b_proj = (const float*)d_in[3];
    float* out = (float*)d_out;

    char* ws = (char*)d_ws;
    size_t off = 0;
    auto alloc = [&](size_t bytes) {
        void* p = ws + off;
        off += (bytes + 255) & ~(size_t)255;
        return p;
    };
    short* x_bf  = (short*)alloc((size_t)TOK * DIM * 2);
    short* wq_bf = (short*)alloc((size_t)3 * DIM * DIM * 2);
    short* wp_bf = (short*)alloc((size_t)DIM * DIM * 2);
    short* Qw    = (short*)alloc((size_t)BHN * SEQ * 64 * 2);
    short* Kw    = (short*)alloc((size_t)BHN * SEQ * 64 * 2);
    short* Vw    = (short*)alloc((size_t)BHN * SEQ * 64 * 2);
    short* Ow    = (short*)alloc((size_t)TOK * DIM * 2);
    float* Vsum  = (float*)alloc((size_t)BHN * 64 * 4);

    int nx4 = TOK * DIM / 4, nq4 = 3 * DIM * DIM / 4, np4 = DIM * DIM / 4;
    int tot4 = nx4 + nq4 + np4;
    cast_all<<<tot4 / 256, 256, 0, stream>>>(x, w_qkv, w_proj, x_bf, wq_bf, wp_bf, nx4, nq4);

    gemm_qkv<<<1152, 256, 0, stream>>>(x_bf, wq_bf, Qw, Kw, Vw);

    vsum_kernel<<<BHN * 64 / 4, 256, 0, stream>>>(Vw, Vsum);

    attn_kernel<<<BHN * 16, 256, 0, stream>>>(Qw, Kw, Vw, Vsum, Ow);

    gemm_proj<<<768, 256, 0, stream>>>(Ow, wp_bf, b_proj, out);
}